// Round 11
// baseline (229.383 us; speedup 1.0000x reference)
//
#include <hip/hip_runtime.h>
#include <hip/hip_bf16.h>
#include <stdint.h>

// Problem constants
#define BS   4
#define LSEQ 2048
#define HID  1024
#define NH   16
#define HD   64
#define M_TOT (BS * LSEQ)   // 8192
#define NKV   (NH * HD)     // 1024
#define PREP_A_BLOCKS 2048

typedef __attribute__((ext_vector_type(8))) short short8x;   // 8 bf16
typedef __attribute__((ext_vector_type(4))) float f32x4;     // MFMA accum

__device__ __forceinline__ float relu_f(float x) { return x > 0.0f ? x : 0.0f; }

__device__ __forceinline__ ushort bf16_rne(float f) {
    uint32_t x = __float_as_uint(f);
    return (ushort)((x + 0x7FFFu + ((x >> 16) & 1u)) >> 16);
}
__device__ __forceinline__ float bf16_to_f(ushort h) {
    return __uint_as_float((uint32_t)h << 16);
}

__device__ __forceinline__ void gload_lds16(const void* g, void* l) {
    typedef __attribute__((address_space(1))) const uint32_t GU;
    typedef __attribute__((address_space(3))) uint32_t LU;
    __builtin_amdgcn_global_load_lds((GU*)g, (LU*)l, 16, 0, 0);
}

// ---------------- fused prep: A hi/lo split + both W hi/lo transposed splits ----------------
// A part: 2048 blocks, 4 float4/thread grid-strided (coalesced rd/wr).
// W part: 512 blocks (64x64 tiles); write-out coalesced: each wave writes
// 8 rows x 128B contiguous segments (was 16B-granule scatter).
__global__ __launch_bounds__(256) void prep(
    const float* __restrict__ A,
    const float* __restrict__ Wv, const float* __restrict__ Wk,
    ushort* __restrict__ Ahi, ushort* __restrict__ Alo,
    ushort* __restrict__ WvhiT, ushort* __restrict__ WvloT,
    ushort* __restrict__ WkhiT, ushort* __restrict__ WkloT)
{
    __shared__ float t[64][65];
    const int bid = blockIdx.x;
    const int tid = threadIdx.x;
    if (bid < PREP_A_BLOCKS) {
#pragma unroll
        for (int g = 0; g < 4; ++g) {
            int i = bid * 256 + tid + g * (PREP_A_BLOCKS * 256);
            float4 v = ((const float4*)A)[i];
            ushort4 h, l;
            h.x = bf16_rne(v.x); l.x = bf16_rne(v.x - bf16_to_f(h.x));
            h.y = bf16_rne(v.y); l.y = bf16_rne(v.y - bf16_to_f(h.y));
            h.z = bf16_rne(v.z); l.z = bf16_rne(v.z - bf16_to_f(h.z));
            h.w = bf16_rne(v.w); l.w = bf16_rne(v.w - bf16_to_f(h.w));
            ((ushort4*)Ahi)[i] = h;
            ((ushort4*)Alo)[i] = l;
        }
    } else {
        int idx = bid - PREP_A_BLOCKS;        // 0..511
        const float* W  = (idx < 256) ? Wv : Wk;
        ushort* hiT     = (idx < 256) ? WvhiT : WkhiT;
        ushort* loT     = (idx < 256) ? WvloT : WkloT;
        int tt = idx & 255;
        int k0 = (tt >> 4) * 64, n0 = (tt & 15) * 64;
#pragma unroll
        for (int it = 0; it < 4; ++it) {
            int r = it * 16 + (tid >> 4);
            int c = (tid & 15) * 4;
            float4 v = *(const float4*)&W[(size_t)(k0 + r) * NKV + n0 + c];
            t[r][c] = v.x; t[r][c + 1] = v.y; t[r][c + 2] = v.z; t[r][c + 3] = v.w;
        }
        __syncthreads();
        // coalesced write-out: n = it*32 + tid>>3 (row), kc = (tid&7)*8
#pragma unroll
        for (int it = 0; it < 2; ++it) {
            int n  = it * 32 + (tid >> 3);
            int kc = (tid & 7) * 8;
            ushort hb[8], lb[8];
#pragma unroll
            for (int j = 0; j < 8; ++j) {
                float f = t[kc + j][n];
                ushort h = bf16_rne(f);
                hb[j] = h;
                lb[j] = bf16_rne(f - bf16_to_f(h));
            }
            size_t o = (size_t)(n0 + n) * 1024 + k0 + kc;
            *(uint4*)&hiT[o] = *(uint4*)&hb[0];
            *(uint4*)&loT[o] = *(uint4*)&lb[0];
        }
    }
}

// ---------------- 128x128 split-bf16 MFMA GEMM (proven template) ----------------
// grid (64, 16): y even -> V path (Wv, 2-term, 32 K-tiles, bf16 V1 out),
//                y odd  -> K path (Wk, 3-term, 48 K-tiles, dot+threshold).
// V/K interleaved in dispatch order to avoid the pure-K tail.
// V: C = Ahi@Whi + Alo@Whi            (err ~2e-3, << 0.071 threshold)
// K: C = Ahi@Whi + Alo@Whi + Ahi@Wlo  (full accuracy for dot>0.5)
__global__ __launch_bounds__(256, 2) void mfma_gemm(
    const ushort* __restrict__ Ahi, const ushort* __restrict__ Alo,
    const ushort* __restrict__ WvhiT, const ushort* __restrict__ WvloT,
    const ushort* __restrict__ WkhiT, const ushort* __restrict__ WkloT,
    const float* __restrict__ bv, const float* __restrict__ bk,
    const float* __restrict__ RH,
    ushort* __restrict__ V1b, unsigned char* __restrict__ validB)
{
    __shared__ ushort As[128 * 64];   // 16 KB, XOR-swizzled 16B chunks
    __shared__ ushort Bsh[128 * 64];  // 16 KB

    const int tid  = threadIdx.x;
    const int lane = tid & 63;
    const int wv   = tid >> 6;        // wave 0..3
    const int wm   = wv >> 1;         // wave row 0/1
    const int wn   = wv & 1;          // wave col 0/1
    const int bm   = blockIdx.x;
    const bool kpath = (blockIdx.y & 1);
    const int bn   = blockIdx.y >> 1;

    const ushort* WT_hi = kpath ? WkhiT : WvhiT;
    const ushort* WT_lo = kpath ? WkloT : WvloT;
    const float*  bias  = kpath ? bk : bv;
    const int KS = kpath ? 48 : 32;   // V path drops the Ahi@Wlo term

    f32x4 acc[4][4];
    const f32x4 z = {0.f, 0.f, 0.f, 0.f};
#pragma unroll
    for (int i = 0; i < 4; ++i)
#pragma unroll
        for (int j = 0; j < 4; ++j) acc[i][j] = z;

    for (int ks = 0; ks < KS; ++ks) {
        const int seg = ks >> 4;
        const int k0  = (ks & 15) << 6;
        const ushort* Aseg = (seg == 1) ? Alo : Ahi;
        const ushort* Wseg = (seg == 2) ? WT_lo : WT_hi;

#pragma unroll
        for (int it = 0; it < 4; ++it) {
            int f = it * 256 + tid;
            int r = f >> 3, c = f & 7;
            const ushort* asrc = Aseg + (size_t)(bm * 128 + r) * 1024 + k0 + ((c ^ (r & 7)) << 3);
            gload_lds16(asrc, &As[(size_t)(it * 256 + wv * 64) * 8]);
        }
#pragma unroll
        for (int it = 0; it < 4; ++it) {
            int f = it * 256 + tid;
            int r = f >> 3, c = f & 7;
            const ushort* bsrc = Wseg + (size_t)(bn * 128 + r) * 1024 + k0 + ((c ^ (r & 7)) << 3);
            gload_lds16(bsrc, &Bsh[(size_t)(it * 256 + wv * 64) * 8]);
        }
        __syncthreads();

        short8x a[4][2], b[4][2];
#pragma unroll
        for (int mi = 0; mi < 4; ++mi)
#pragma unroll
            for (int k2 = 0; k2 < 2; ++k2) {
                int row = wm * 64 + mi * 16 + (lane & 15);
                int ch  = k2 * 4 + (lane >> 4);
                a[mi][k2] = *(const short8x*)((const char*)As + row * 128 + ((ch ^ (row & 7)) << 4));
            }
#pragma unroll
        for (int ni = 0; ni < 4; ++ni)
#pragma unroll
            for (int k2 = 0; k2 < 2; ++k2) {
                int row = wn * 64 + ni * 16 + (lane & 15);
                int ch  = k2 * 4 + (lane >> 4);
                b[ni][k2] = *(const short8x*)((const char*)Bsh + row * 128 + ((ch ^ (row & 7)) << 4));
            }

#pragma unroll
        for (int k2 = 0; k2 < 2; ++k2)
#pragma unroll
            for (int mi = 0; mi < 4; ++mi)
#pragma unroll
                for (int ni = 0; ni < 4; ++ni)
                    acc[mi][ni] = __builtin_amdgcn_mfma_f32_16x16x32_bf16(
                        a[mi][k2], b[ni][k2], acc[mi][ni], 0, 0, 0);
        __syncthreads();
    }

    // epilogue ; C/D layout: col = lane&15, row = (lane>>4)*4 + reg
    if (!kpath) {
#pragma unroll
        for (int mi = 0; mi < 4; ++mi)
#pragma unroll
            for (int ni = 0; ni < 4; ++ni) {
                int row0 = bm * 128 + wm * 64 + mi * 16 + (lane >> 4) * 4;
                int col  = bn * 128 + wn * 64 + ni * 16 + (lane & 15);
                float bc = bias[col];
#pragma unroll
                for (int r = 0; r < 4; ++r)
                    V1b[(size_t)(row0 + r) * NKV + col] =
                        bf16_rne(relu_f(acc[mi][ni][r] + bc));
            }
    } else {
        const int head = bn * 2 + wn;
        float rhw[4], bcs[4];
#pragma unroll
        for (int ni = 0; ni < 4; ++ni) {
            int ch = ni * 16 + (lane & 15);                 // col within head
            rhw[ni] = RH[head * HD + ch];
            bcs[ni] = bias[bn * 128 + wn * 64 + ch];
        }
#pragma unroll
        for (int mi = 0; mi < 4; ++mi) {
            float s[4];
#pragma unroll
            for (int r = 0; r < 4; ++r) {
                float v = 0.f;
#pragma unroll
                for (int ni = 0; ni < 4; ++ni)
                    v += relu_f(acc[mi][ni][r] + bcs[ni]) * rhw[ni];
                s[r] = v;
            }
#pragma unroll
            for (int m = 1; m < 16; m <<= 1)
#pragma unroll
                for (int r = 0; r < 4; ++r)
                    s[r] += __shfl_xor(s[r], m);
            if ((lane & 15) == 0) {
#pragma unroll
                for (int r = 0; r < 4; ++r) {
                    int grow = bm * 128 + wm * 64 + mi * 16 + (lane >> 4) * 4 + r;
                    int bb = grow >> 11, ll = grow & 2047;
                    validB[((size_t)bb * NH + head) * LSEQ + ll] = (s[r] > 0.5f) ? 1 : 0;
                }
            }
        }
    }
}

// ---------------- parallel register-map extraction ----------------
__global__ __launch_bounds__(256) void scan_kernel(
    const unsigned char* __restrict__ validB,
    short* __restrict__ idxb)   // [M_TOT][NH][8]: slots 0..3 fwd, 4..7 bwd
{
    const int bh = blockIdx.x;      // 0..63
    const int b  = bh >> 4;
    const int h  = bh & 15;
    const unsigned char* v = validB + ((size_t)b * NH + h) * LSEQ;

    __shared__ uint64_t words[LSEQ / 64];

    const int tid  = threadIdx.x;
    const int lane = tid & 63;
    const int wv   = tid >> 6;

#pragma unroll
    for (int it = 0; it < LSEQ / 256; ++it) {
        int p = it * 256 + wv * 64 + lane;
        uint64_t m = __ballot(v[p] != 0);
        if (lane == 0) {
            if ((p >> 6) == 0) m &= ~1ull;
            words[p >> 6] = m;
        }
    }
    __syncthreads();

#pragma unroll
    for (int it = 0; it < LSEQ / 256; ++it) {
        int l = it * 256 + tid;
        ushort f[4] = {0, 0, 0, 0};
        ushort g[4] = {0, 0, 0, 0};
        if (l > 0) {
            {   // forward: last 4 set bits <= l
                int wi = l >> 6, bi = l & 63;
                uint64_t m = words[wi] & ((bi == 63) ? ~0ull : ((2ull << bi) - 1));
                int cnt = 0;
                while (cnt < 4) {
                    if (m == 0) { if (wi == 0) break; m = words[--wi]; continue; }
                    int p = 63 - __clzll(m);
                    f[cnt++] = (ushort)(wi * 64 + p);
                    m &= ~(1ull << p);
                }
            }
            {   // backward: first 4 set bits >= l, value min(p+1, L-1)
                int wi = l >> 6, bi = l & 63;
                uint64_t m = words[wi] & (~0ull << bi);
                int cnt = 0;
                while (cnt < 4) {
                    if (m == 0) { if (wi == (LSEQ / 64) - 1) break; m = words[++wi]; continue; }
                    int p = __ffsll((long long)m) - 1;
                    int pos = wi * 64 + p;
                    g[cnt++] = (ushort)((pos >= LSEQ - 1) ? (LSEQ - 1) : (pos + 1));
                    m &= m - 1;
                }
            }
        }
        uint4 pk;
        pk.x = (uint32_t)f[0] | ((uint32_t)f[1] << 16);
        pk.y = (uint32_t)f[2] | ((uint32_t)f[3] << 16);
        pk.z = (uint32_t)g[0] | ((uint32_t)g[1] << 16);
        pk.w = (uint32_t)g[2] | ((uint32_t)g[3] << 16);
        *(uint4*)(idxb + (((size_t)(b * LSEQ + l)) * NH + h) * 8) = pk;
    }
}

// ---------------- weighted 8-way gather (bf16 V1) ----------------
__global__ __launch_bounds__(256) void gather_kernel(
    const ushort* __restrict__ V1b,
    const short* __restrict__ idxb,
    const float* __restrict__ bw,
    float* __restrict__ out)
{
    int wid  = (blockIdx.x * 256 + threadIdx.x) >> 6;
    int lane = threadIdx.x & 63;
    int gr   = wid >> 4;
    int h    = wid & 15;
    int b    = gr >> 11;

    const ushort4* ip = (const ushort4*)(idxb + ((size_t)gr * NH + h) * 8);
    ushort4 i0 = ip[0];
    ushort4 i1 = ip[1];

    const float* wp     = bw + h * 8;
    const ushort* vbase = V1b + (size_t)b * LSEQ * NKV + h * HD + lane;

    float acc = wp[0] * bf16_to_f(vbase[(size_t)i0.x * NKV]) +
                wp[1] * bf16_to_f(vbase[(size_t)i0.y * NKV]) +
                wp[2] * bf16_to_f(vbase[(size_t)i0.z * NKV]) +
                wp[3] * bf16_to_f(vbase[(size_t)i0.w * NKV]) +
                wp[4] * bf16_to_f(vbase[(size_t)i1.x * NKV]) +
                wp[5] * bf16_to_f(vbase[(size_t)i1.y * NKV]) +
                wp[6] * bf16_to_f(vbase[(size_t)i1.z * NKV]) +
                wp[7] * bf16_to_f(vbase[(size_t)i1.w * NKV]);

    out[(size_t)gr * NKV + h * HD + lane] = acc;
}

extern "C" void kernel_launch(void* const* d_in, const int* in_sizes, int n_in,
                              void* d_out, int out_size, void* d_ws, size_t ws_size,
                              hipStream_t stream)
{
    const float* hs = (const float*)d_in[0];  // [4,2048,1024]
    const float* Wk = (const float*)d_in[1];  // [1024,1024]
    const float* bk = (const float*)d_in[2];  // [1024]
    const float* Wv = (const float*)d_in[3];  // [1024,1024]
    const float* bv = (const float*)d_in[4];  // [1024]
    const float* RH = (const float*)d_in[5];  // [16,64]
    const float* bw = (const float*)d_in[6];  // [16,8]
    float* out = (float*)d_out;

    char* ws = (char*)d_ws;
    size_t o = 0;
    ushort* V1b    = (ushort*)(ws + o); o += (size_t)M_TOT * NKV * 2;      // 16 MiB
    ushort* Ahi    = (ushort*)(ws + o); o += (size_t)M_TOT * HID * 2;      // 16 MiB
    ushort* Alo    = (ushort*)(ws + o); o += (size_t)M_TOT * HID * 2;      // 16 MiB
    ushort* WvhiT  = (ushort*)(ws + o); o += (size_t)HID * NKV * 2;        // 2 MiB
    ushort* WvloT  = (ushort*)(ws + o); o += (size_t)HID * NKV * 2;
    ushort* WkhiT  = (ushort*)(ws + o); o += (size_t)HID * NKV * 2;
    ushort* WkloT  = (ushort*)(ws + o); o += (size_t)HID * NKV * 2;
    unsigned char* validB = (unsigned char*)(ws + o); o += (size_t)BS * NH * LSEQ; // 128 KiB
    short* idxb    = (short*)(ws + o);  o += (size_t)M_TOT * NH * 8 * 2;   // 2 MiB

    prep<<<PREP_A_BLOCKS + 512, 256, 0, stream>>>(hs, Wv, Wk, Ahi, Alo,
                                                  WvhiT, WvloT, WkhiT, WkloT);
    mfma_gemm<<<dim3(M_TOT / 128, 16), 256, 0, stream>>>(
        Ahi, Alo, WvhiT, WvloT, WkhiT, WkloT, bv, bk, RH, V1b, validB);
    scan_kernel<<<BS * NH, 256, 0, stream>>>(validB, idxb);
    gather_kernel<<<(M_TOT * NH) / 4, 256, 0, stream>>>(V1b, idxb, bw, out);
}

// Round 12
// 225.093 us; speedup vs baseline: 1.0191x; 1.0191x over previous
//
#include <hip/hip_runtime.h>
#include <hip/hip_bf16.h>
#include <stdint.h>

// Problem constants
#define BS   4
#define LSEQ 2048
#define HID  1024
#define NH   16
#define HD   64
#define M_TOT (BS * LSEQ)   // 8192
#define NKV   (NH * HD)     // 1024
#define PREP_A_BLOCKS 2048

typedef __attribute__((ext_vector_type(8))) short short8x;   // 8 bf16
typedef __attribute__((ext_vector_type(4))) float f32x4;     // MFMA accum

__device__ __forceinline__ float relu_f(float x) { return x > 0.0f ? x : 0.0f; }

__device__ __forceinline__ ushort bf16_rne(float f) {
    uint32_t x = __float_as_uint(f);
    return (ushort)((x + 0x7FFFu + ((x >> 16) & 1u)) >> 16);
}
__device__ __forceinline__ float bf16_to_f(ushort h) {
    return __uint_as_float((uint32_t)h << 16);
}

__device__ __forceinline__ void gload_lds16(const void* g, void* l) {
    typedef __attribute__((address_space(1))) const uint32_t GU;
    typedef __attribute__((address_space(3))) uint32_t LU;
    __builtin_amdgcn_global_load_lds((GU*)g, (LU*)l, 16, 0, 0);
}

// ---------------- fused prep: A hi/lo split + both W hi/lo transposed splits ----------------
__global__ __launch_bounds__(256) void prep(
    const float* __restrict__ A,
    const float* __restrict__ Wv, const float* __restrict__ Wk,
    ushort* __restrict__ Ahi, ushort* __restrict__ Alo,
    ushort* __restrict__ WvhiT, ushort* __restrict__ WvloT,
    ushort* __restrict__ WkhiT, ushort* __restrict__ WkloT)
{
    __shared__ float t[64][65];
    const int bid = blockIdx.x;
    const int tid = threadIdx.x;
    if (bid < PREP_A_BLOCKS) {
#pragma unroll
        for (int g = 0; g < 4; ++g) {
            int i = bid * 256 + tid + g * (PREP_A_BLOCKS * 256);
            float4 v = ((const float4*)A)[i];
            ushort4 h, l;
            h.x = bf16_rne(v.x); l.x = bf16_rne(v.x - bf16_to_f(h.x));
            h.y = bf16_rne(v.y); l.y = bf16_rne(v.y - bf16_to_f(h.y));
            h.z = bf16_rne(v.z); l.z = bf16_rne(v.z - bf16_to_f(h.z));
            h.w = bf16_rne(v.w); l.w = bf16_rne(v.w - bf16_to_f(h.w));
            ((ushort4*)Ahi)[i] = h;
            ((ushort4*)Alo)[i] = l;
        }
    } else {
        int idx = bid - PREP_A_BLOCKS;        // 0..511
        const float* W  = (idx < 256) ? Wv : Wk;
        ushort* hiT     = (idx < 256) ? WvhiT : WkhiT;
        ushort* loT     = (idx < 256) ? WvloT : WkloT;
        int tt = idx & 255;
        int k0 = (tt >> 4) * 64, n0 = (tt & 15) * 64;
#pragma unroll
        for (int it = 0; it < 4; ++it) {
            int r = it * 16 + (tid >> 4);
            int c = (tid & 15) * 4;
            float4 v = *(const float4*)&W[(size_t)(k0 + r) * NKV + n0 + c];
            t[r][c] = v.x; t[r][c + 1] = v.y; t[r][c + 2] = v.z; t[r][c + 3] = v.w;
        }
        __syncthreads();
#pragma unroll
        for (int it = 0; it < 2; ++it) {
            int n  = it * 32 + (tid >> 3);
            int kc = (tid & 7) * 8;
            ushort hb[8], lb[8];
#pragma unroll
            for (int j = 0; j < 8; ++j) {
                float f = t[kc + j][n];
                ushort h = bf16_rne(f);
                hb[j] = h;
                lb[j] = bf16_rne(f - bf16_to_f(h));
            }
            size_t o = (size_t)(n0 + n) * 1024 + k0 + kc;
            *(uint4*)&hiT[o] = *(uint4*)&hb[0];
            *(uint4*)&loT[o] = *(uint4*)&lb[0];
        }
    }
}

// ---------------- 128x128 split-bf16 MFMA GEMM (round-10 proven config) ----------------
// grid (64, 16): y 0..7 -> V path (Wv, 2-term, 32 K-tiles, bf16 head-major V1),
//                y 8..15 -> K path (Wk, 3-term, 48 K-tiles, dot+threshold).
// V1b layout: [b][h][l][d] (head-major) so gather's per-(b,h) working set is a
// contiguous 256 KB window (L2-resident).
__global__ __launch_bounds__(256, 2) void mfma_gemm(
    const ushort* __restrict__ Ahi, const ushort* __restrict__ Alo,
    const ushort* __restrict__ WvhiT, const ushort* __restrict__ WvloT,
    const ushort* __restrict__ WkhiT, const ushort* __restrict__ WkloT,
    const float* __restrict__ bv, const float* __restrict__ bk,
    const float* __restrict__ RH,
    ushort* __restrict__ V1b, unsigned char* __restrict__ validB)
{
    __shared__ ushort As[128 * 64];   // 16 KB, XOR-swizzled 16B chunks
    __shared__ ushort Bsh[128 * 64];  // 16 KB

    const int tid  = threadIdx.x;
    const int lane = tid & 63;
    const int wv   = tid >> 6;        // wave 0..3
    const int wm   = wv >> 1;         // wave row 0/1
    const int wn   = wv & 1;          // wave col 0/1
    const int bm   = blockIdx.x;
    const bool kpath = (blockIdx.y >= 8);
    const int bn   = blockIdx.y & 7;

    const ushort* WT_hi = kpath ? WkhiT : WvhiT;
    const ushort* WT_lo = kpath ? WkloT : WvloT;
    const float*  bias  = kpath ? bk : bv;
    const int KS = kpath ? 48 : 32;   // V path drops the Ahi@Wlo term

    f32x4 acc[4][4];
    const f32x4 z = {0.f, 0.f, 0.f, 0.f};
#pragma unroll
    for (int i = 0; i < 4; ++i)
#pragma unroll
        for (int j = 0; j < 4; ++j) acc[i][j] = z;

    for (int ks = 0; ks < KS; ++ks) {
        const int seg = ks >> 4;
        const int k0  = (ks & 15) << 6;
        const ushort* Aseg = (seg == 1) ? Alo : Ahi;
        const ushort* Wseg = (seg == 2) ? WT_lo : WT_hi;

#pragma unroll
        for (int it = 0; it < 4; ++it) {
            int f = it * 256 + tid;
            int r = f >> 3, c = f & 7;
            const ushort* asrc = Aseg + (size_t)(bm * 128 + r) * 1024 + k0 + ((c ^ (r & 7)) << 3);
            gload_lds16(asrc, &As[(size_t)(it * 256 + wv * 64) * 8]);
        }
#pragma unroll
        for (int it = 0; it < 4; ++it) {
            int f = it * 256 + tid;
            int r = f >> 3, c = f & 7;
            const ushort* bsrc = Wseg + (size_t)(bn * 128 + r) * 1024 + k0 + ((c ^ (r & 7)) << 3);
            gload_lds16(bsrc, &Bsh[(size_t)(it * 256 + wv * 64) * 8]);
        }
        __syncthreads();

        short8x a[4][2], b[4][2];
#pragma unroll
        for (int mi = 0; mi < 4; ++mi)
#pragma unroll
            for (int k2 = 0; k2 < 2; ++k2) {
                int row = wm * 64 + mi * 16 + (lane & 15);
                int ch  = k2 * 4 + (lane >> 4);
                a[mi][k2] = *(const short8x*)((const char*)As + row * 128 + ((ch ^ (row & 7)) << 4));
            }
#pragma unroll
        for (int ni = 0; ni < 4; ++ni)
#pragma unroll
            for (int k2 = 0; k2 < 2; ++k2) {
                int row = wn * 64 + ni * 16 + (lane & 15);
                int ch  = k2 * 4 + (lane >> 4);
                b[ni][k2] = *(const short8x*)((const char*)Bsh + row * 128 + ((ch ^ (row & 7)) << 4));
            }

#pragma unroll
        for (int k2 = 0; k2 < 2; ++k2)
#pragma unroll
            for (int mi = 0; mi < 4; ++mi)
#pragma unroll
                for (int ni = 0; ni < 4; ++ni)
                    acc[mi][ni] = __builtin_amdgcn_mfma_f32_16x16x32_bf16(
                        a[mi][k2], b[ni][k2], acc[mi][ni], 0, 0, 0);
        __syncthreads();
    }

    // epilogue ; C/D layout: col = lane&15, row = (lane>>4)*4 + reg
    if (!kpath) {
        const int head = bn * 2 + wn;                 // 64-col wave column == head
#pragma unroll
        for (int mi = 0; mi < 4; ++mi)
#pragma unroll
            for (int ni = 0; ni < 4; ++ni) {
                int row0 = bm * 128 + wm * 64 + mi * 16 + (lane >> 4) * 4;
                int ch   = ni * 16 + (lane & 15);     // d within head
                float bc = bias[head * HD + ch];
#pragma unroll
                for (int r = 0; r < 4; ++r) {
                    int grow = row0 + r;
                    int bb = grow >> 11, ll = grow & 2047;
                    // head-major: [b][h][l][d]
                    V1b[(((size_t)bb * NH + head) * LSEQ + ll) * HD + ch] =
                        bf16_rne(relu_f(acc[mi][ni][r] + bc));
                }
            }
    } else {
        const int head = bn * 2 + wn;
        float rhw[4], bcs[4];
#pragma unroll
        for (int ni = 0; ni < 4; ++ni) {
            int ch = ni * 16 + (lane & 15);                 // col within head
            rhw[ni] = RH[head * HD + ch];
            bcs[ni] = bias[bn * 128 + wn * 64 + ch];
        }
#pragma unroll
        for (int mi = 0; mi < 4; ++mi) {
            float s[4];
#pragma unroll
            for (int r = 0; r < 4; ++r) {
                float v = 0.f;
#pragma unroll
                for (int ni = 0; ni < 4; ++ni)
                    v += relu_f(acc[mi][ni][r] + bcs[ni]) * rhw[ni];
                s[r] = v;
            }
#pragma unroll
            for (int m = 1; m < 16; m <<= 1)
#pragma unroll
                for (int r = 0; r < 4; ++r)
                    s[r] += __shfl_xor(s[r], m);
            if ((lane & 15) == 0) {
#pragma unroll
                for (int r = 0; r < 4; ++r) {
                    int grow = bm * 128 + wm * 64 + mi * 16 + (lane >> 4) * 4 + r;
                    int bb = grow >> 11, ll = grow & 2047;
                    validB[((size_t)bb * NH + head) * LSEQ + ll] = (s[r] > 0.5f) ? 1 : 0;
                }
            }
        }
    }
}

// ---------------- parallel register-map extraction ----------------
__global__ __launch_bounds__(256) void scan_kernel(
    const unsigned char* __restrict__ validB,
    short* __restrict__ idxb)   // [M_TOT][NH][8]: slots 0..3 fwd, 4..7 bwd
{
    const int bh = blockIdx.x;      // 0..63
    const int b  = bh >> 4;
    const int h  = bh & 15;
    const unsigned char* v = validB + ((size_t)b * NH + h) * LSEQ;

    __shared__ uint64_t words[LSEQ / 64];

    const int tid  = threadIdx.x;
    const int lane = tid & 63;
    const int wv   = tid >> 6;

#pragma unroll
    for (int it = 0; it < LSEQ / 256; ++it) {
        int p = it * 256 + wv * 64 + lane;
        uint64_t m = __ballot(v[p] != 0);
        if (lane == 0) {
            if ((p >> 6) == 0) m &= ~1ull;
            words[p >> 6] = m;
        }
    }
    __syncthreads();

#pragma unroll
    for (int it = 0; it < LSEQ / 256; ++it) {
        int l = it * 256 + tid;
        ushort f[4] = {0, 0, 0, 0};
        ushort g[4] = {0, 0, 0, 0};
        if (l > 0) {
            {   // forward: last 4 set bits <= l
                int wi = l >> 6, bi = l & 63;
                uint64_t m = words[wi] & ((bi == 63) ? ~0ull : ((2ull << bi) - 1));
                int cnt = 0;
                while (cnt < 4) {
                    if (m == 0) { if (wi == 0) break; m = words[--wi]; continue; }
                    int p = 63 - __clzll(m);
                    f[cnt++] = (ushort)(wi * 64 + p);
                    m &= ~(1ull << p);
                }
            }
            {   // backward: first 4 set bits >= l, value min(p+1, L-1)
                int wi = l >> 6, bi = l & 63;
                uint64_t m = words[wi] & (~0ull << bi);
                int cnt = 0;
                while (cnt < 4) {
                    if (m == 0) { if (wi == (LSEQ / 64) - 1) break; m = words[++wi]; continue; }
                    int p = __ffsll((long long)m) - 1;
                    int pos = wi * 64 + p;
                    g[cnt++] = (ushort)((pos >= LSEQ - 1) ? (LSEQ - 1) : (pos + 1));
                    m &= m - 1;
                }
            }
        }
        uint4 pk;
        pk.x = (uint32_t)f[0] | ((uint32_t)f[1] << 16);
        pk.y = (uint32_t)f[2] | ((uint32_t)f[3] << 16);
        pk.z = (uint32_t)g[0] | ((uint32_t)g[1] << 16);
        pk.w = (uint32_t)g[2] | ((uint32_t)g[3] << 16);
        *(uint4*)(idxb + (((size_t)(b * LSEQ + l)) * NH + h) * 8) = pk;
    }
}

// ---------------- weighted 8-way gather (bf16 V1, head-major) ----------------
__global__ __launch_bounds__(256) void gather_kernel(
    const ushort* __restrict__ V1b,   // [b][h][l][d]
    const short* __restrict__ idxb,
    const float* __restrict__ bw,
    float* __restrict__ out)
{
    int wid  = (blockIdx.x * 256 + threadIdx.x) >> 6;
    int lane = threadIdx.x & 63;
    int gr   = wid >> 4;
    int h    = wid & 15;
    int b    = gr >> 11;

    const ushort4* ip = (const ushort4*)(idxb + ((size_t)gr * NH + h) * 8);
    ushort4 i0 = ip[0];
    ushort4 i1 = ip[1];

    const float* wp     = bw + h * 8;
    const ushort* vbase = V1b + ((size_t)b * NH + h) * LSEQ * HD + lane;

    float acc = wp[0] * bf16_to_f(vbase[(size_t)i0.x * HD]) +
                wp[1] * bf16_to_f(vbase[(size_t)i0.y * HD]) +
                wp[2] * bf16_to_f(vbase[(size_t)i0.z * HD]) +
                wp[3] * bf16_to_f(vbase[(size_t)i0.w * HD]) +
                wp[4] * bf16_to_f(vbase[(size_t)i1.x * HD]) +
                wp[5] * bf16_to_f(vbase[(size_t)i1.y * HD]) +
                wp[6] * bf16_to_f(vbase[(size_t)i1.z * HD]) +
                wp[7] * bf16_to_f(vbase[(size_t)i1.w * HD]);

    out[(size_t)gr * NKV + h * HD + lane] = acc;
}

extern "C" void kernel_launch(void* const* d_in, const int* in_sizes, int n_in,
                              void* d_out, int out_size, void* d_ws, size_t ws_size,
                              hipStream_t stream)
{
    const float* hs = (const float*)d_in[0];  // [4,2048,1024]
    const float* Wk = (const float*)d_in[1];  // [1024,1024]
    const float* bk = (const float*)d_in[2];  // [1024]
    const float* Wv = (const float*)d_in[3];  // [1024,1024]
    const float* bv = (const float*)d_in[4];  // [1024]
    const float* RH = (const float*)d_in[5];  // [16,64]
    const float* bw = (const float*)d_in[6];  // [16,8]
    float* out = (float*)d_out;

    char* ws = (char*)d_ws;
    size_t o = 0;
    ushort* V1b    = (ushort*)(ws + o); o += (size_t)M_TOT * NKV * 2;      // 16 MiB
    ushort* Ahi    = (ushort*)(ws + o); o += (size_t)M_TOT * HID * 2;      // 16 MiB
    ushort* Alo    = (ushort*)(ws + o); o += (size_t)M_TOT * HID * 2;      // 16 MiB
    ushort* WvhiT  = (ushort*)(ws + o); o += (size_t)HID * NKV * 2;        // 2 MiB
    ushort* WvloT  = (ushort*)(ws + o); o += (size_t)HID * NKV * 2;
    ushort* WkhiT  = (ushort*)(ws + o); o += (size_t)HID * NKV * 2;
    ushort* WkloT  = (ushort*)(ws + o); o += (size_t)HID * NKV * 2;
    unsigned char* validB = (unsigned char*)(ws + o); o += (size_t)BS * NH * LSEQ; // 128 KiB
    short* idxb    = (short*)(ws + o);  o += (size_t)M_TOT * NH * 8 * 2;   // 2 MiB

    prep<<<PREP_A_BLOCKS + 512, 256, 0, stream>>>(hs, Wv, Wk, Ahi, Alo,
                                                  WvhiT, WvloT, WkhiT, WkloT);
    mfma_gemm<<<dim3(M_TOT / 128, 16), 256, 0, stream>>>(
        Ahi, Alo, WvhiT, WvloT, WkhiT, WkloT, bv, bk, RH, V1b, validB);
    scan_kernel<<<BS * NH, 256, 0, stream>>>(validB, idxb);
    gather_kernel<<<(M_TOT * NH) / 4, 256, 0, stream>>>(V1b, idxb, bw, out);
}